// Round 17
// baseline (81.592 us; speedup 1.0000x reference)
//
#include <hip/hip_runtime.h>
#include <hip/hip_bf16.h>

typedef __bf16 bf16_t;
typedef __bf16 bf16x4 __attribute__((ext_vector_type(4)));
typedef __bf16 bf16x8 __attribute__((ext_vector_type(8)));
typedef float f32x4 __attribute__((ext_vector_type(4)));

#define S_LEN 2048
#define DMODEL 1024
#define NHEADS 16
#define HDIM 64
#define BROWS 4096   // B * S
#define QKVN 3072    // fused QKV output width

__device__ __forceinline__ void async16(const void* g, void* l) {
  __builtin_amdgcn_global_load_lds(
      (const __attribute__((address_space(1))) void*)g,
      (__attribute__((address_space(3))) void*)l, 16, 0, 0);
}

// ------------- fused f32 -> bf16 conversion (x, Wq, Wk, Wv, Wo) -------------
__global__ __launch_bounds__(256) void cvt_all_kernel(
    const float* __restrict__ x, const float* __restrict__ Wq,
    const float* __restrict__ Wk, const float* __restrict__ Wv,
    const float* __restrict__ Wo, bf16_t* __restrict__ dst) {
  const int i = blockIdx.x * 256 + threadIdx.x;  // float4 index
  constexpr int XN4 = (BROWS * DMODEL) / 4;      // 1048576
  constexpr int WN4 = (DMODEL * DMODEL) / 4;     // 262144
  const float* src;
  size_t off;
  if (i < XN4) {
    src = x;
    off = (size_t)i;
  } else {
    const int wi = i - XN4;
    const int w = wi >> 18;
    off = (size_t)(wi & (WN4 - 1));
    src = (w == 0) ? Wq : (w == 1) ? Wk : (w == 2) ? Wv : Wo;
  }
  const float4 v = *(const float4*)(src + off * 4);
  bf16x4 o;
  o[0] = (bf16_t)v.x;
  o[1] = (bf16_t)v.y;
  o[2] = (bf16_t)v.z;
  o[3] = (bf16_t)v.w;
  *(bf16x4*)(dst + (size_t)i * 4) = o;
}

#define BARR __builtin_amdgcn_s_barrier()
#define LGKM0 asm volatile("s_waitcnt lgkmcnt(0)" ::: "memory")
#define VMC8 asm volatile("s_waitcnt vmcnt(8)" ::: "memory")
#define VMC12 asm volatile("s_waitcnt vmcnt(12)" ::: "memory")
#define VMC0 asm volatile("s_waitcnt vmcnt(0)" ::: "memory")

// ========== 64x192 GEMM (QKV): BK=32, 4 blocks/CU, 4 barrier domains ========
// Round-17: extend the proven occupancy lever (r15: 2 blk/CU -4us, r16 O:
// -5.4us).  Tile 64x192, BK=32, 128 thr (2 waves split N -> wave-tile 64x96,
// same LDS ratio as r15).  LDS 32KB -> grid 64x16 = 1024 = 4 blocks/CU.
// 64B LDS rows (4 slots): swizzle slot^(r&3) -> 2-way bank = free (m136).
// Loop = r15 race-free template; 8 stage-instr/tile (A2+B6) -> VMC8 gates.
__global__ __launch_bounds__(128, 2) void gemm_qkv_kernel(
    const bf16_t* __restrict__ A, const bf16_t* __restrict__ W,
    const float* __restrict__ bq, const float* __restrict__ bk,
    const float* __restrict__ bv, bf16_t* __restrict__ C) {
  constexpr int Kd = 1024;
  __shared__ char lds[32768];  // A: 2buf*4KB = 8KB, B: 2buf*12KB = 24KB
  char* ldsA = lds;            // + buf*4096
  char* ldsB = lds + 8192;     // + buf*12288

  const int m0 = blockIdx.x * 64;
  const int n0 = blockIdx.y * 192;

  const int tid = threadIdx.x;  // 0..127
  const int lane = tid & 63;
  const int wc = tid >> 6;  // 0..1 (96-col halves)
  const int fr = lane & 15;
  const int l16 = lane >> 4;

  f32x4 acc[4][6] = {};
  bf16x8 aS[4], bB[6];

  // A tile: 64 rows x 64B = 256 chunks -> 2 instr/thread
  auto stageA = [&](int buf, int kt) {
#pragma unroll
    for (int l = 0; l < 2; ++l) {
      const int idx = l * 128 + tid;
      const int r = idx >> 2;  // 0..63
      const int slot = idx & 3;
      async16((const char*)(A + (size_t)(m0 + r) * Kd + kt * 32 +
                            ((slot ^ (r & 3)) << 3)),
              ldsA + buf * 4096 + r * 64 + slot * 16);
    }
  };
  // B tile: 192 rows x 64B = 768 chunks -> 6 instr/thread
  auto stageB = [&](int buf, int kt) {
#pragma unroll
    for (int l = 0; l < 6; ++l) {
      const int idx = l * 128 + tid;
      const int r = idx >> 2;  // 0..191
      const int slot = idx & 3;
      async16((const char*)(W + (size_t)(n0 + r) * Kd + kt * 32 +
                            ((slot ^ (r & 3)) << 3)),
              ldsB + buf * 12288 + r * 64 + slot * 16);
    }
  };

  auto rdA = [&](int buf, int row) -> bf16x8 {
    return *(const bf16x8*)(ldsA + buf * 4096 + row * 64 +
                            ((l16 ^ (row & 3)) << 4));
  };
  auto rdB = [&](int buf, int row) -> bf16x8 {
    return *(const bf16x8*)(ldsB + buf * 12288 + row * 64 +
                            ((l16 ^ (row & 3)) << 4));
  };

  // prologue: tile0 -> buf0 (8 instr), tile1 -> buf1 (8); certify tile0.
  stageA(0, 0);
  stageB(0, 0);
  stageA(1, 1);
  stageB(1, 1);
  VMC8;  // 16 outstanding -> retire oldest 8 = all of tile0 (own)
  BARR;  // barrier-release certifies tile0 across both waves

#pragma unroll 1
  for (int t = 0; t < 32; ++t) {
    const int buf = t & 1;
    // reads: A 4 + B 6 = 10 x ds_read_b128 per wave
#pragma unroll
    for (int m_ = 0; m_ < 4; ++m_) aS[m_] = rdA(buf, m_ * 16 + fr);
#pragma unroll
    for (int n_ = 0; n_ < 6; ++n_) bB[n_] = rdB(buf, wc * 96 + n_ * 16 + fr);
    LGKM0;  // own reads retired...
    BARR;   // ...all waves' reads retired -> buf safe to overwrite
    if (t + 2 < 32) {
      stageA(buf, t + 2);
      stageB(buf, t + 2);
    }
    // 24 MFMA
    __builtin_amdgcn_s_setprio(1);
#pragma unroll
    for (int m_ = 0; m_ < 4; ++m_)
#pragma unroll
      for (int n_ = 0; n_ < 6; ++n_)
        acc[m_][n_] = __builtin_amdgcn_mfma_f32_16x16x32_bf16(
            aS[m_], bB[n_], acc[m_][n_], 0, 0, 0);
    __builtin_amdgcn_s_setprio(0);
    // certify tile t+1 (VMC -> BARR -> next iter's reads)
    if (t < 31) {
      if (t + 2 < 32) {
        VMC8;  // outstanding t+1's 8 + t+2's 8 -> retire t+1's
      } else {
        VMC0;  // t=30: only t31's 8 outstanding
      }
      BARR;
    }
  }

  // epilogue: C/D layout col = lane&15, row = (lane>>4)*4 + reg  [m89]
  const int cr = l16 * 4;
#pragma unroll
  for (int nf = 0; nf < 6; ++nf) {
    const int col = n0 + wc * 96 + nf * 16 + fr;  // 0..3071
    const int mat = col >> 10;
    const float* bp = (mat == 0) ? bq : (mat == 1) ? bk : bv;
    const float bval = bp[col & 1023];
#pragma unroll
    for (int mf = 0; mf < 4; ++mf) {
      const int row = m0 + mf * 16 + cr;
#pragma unroll
      for (int r = 0; r < 4; ++r)
        C[(size_t)(row + r) * QKVN + col] = (bf16_t)(acc[mf][nf][r] + bval);
    }
  }
}

// ====== 64x128 GEMM (O-proj): r16 verified, 2 waves, 2 blocks/CU ============
__global__ __launch_bounds__(128) void gemm_o_kernel(
    const bf16_t* __restrict__ A, const bf16_t* __restrict__ W,
    const float* __restrict__ bias, float* __restrict__ out) {
  constexpr int Kd = 1024, Nd = 1024;
  __shared__ char lds[49152];  // A: 2buf*8KB = 16KB, B: 2buf*16KB = 32KB
  char* ldsA = lds;            // + buf*8192
  char* ldsB = lds + 16384;    // + buf*16384

  const int m0 = blockIdx.x * 64;
  const int n0 = blockIdx.y * 128;

  const int tid = threadIdx.x;  // 0..127
  const int lane = tid & 63;
  const int wid = tid >> 6;  // 0..1 (64-col halves)
  const int fr = lane & 15;
  const int l16 = lane >> 4;

  f32x4 acc[4][4] = {};
  bf16x8 aS[4][2], bB[4][2];

  auto stageA = [&](int buf, int kt) {
#pragma unroll
    for (int l = 0; l < 4; ++l) {
      const int idx = l * 128 + tid;
      const int r = idx >> 3;  // 0..63
      const int slot = idx & 7;
      async16((const char*)(A + (size_t)(m0 + r) * Kd + kt * 64 +
                            ((slot ^ (r & 7)) << 3)),
              ldsA + buf * 8192 + r * 128 + slot * 16);
    }
  };
  auto stageB = [&](int buf, int kt) {
#pragma unroll
    for (int l = 0; l < 8; ++l) {
      const int idx = l * 128 + tid;
      const int r = idx >> 3;  // 0..127
      const int slot = idx & 7;
      async16((const char*)(W + (size_t)(n0 + r) * Kd + kt * 64 +
                            ((slot ^ (r & 7)) << 3)),
              ldsB + buf * 16384 + r * 128 + slot * 16);
    }
  };

  auto rdA = [&](int buf, int row, int ks) -> bf16x8 {
    return *(const bf16x8*)(ldsA + buf * 8192 + row * 128 +
                            ((((ks << 2) + l16) ^ (row & 7)) << 4));
  };
  auto rdB = [&](int buf, int row, int ks) -> bf16x8 {
    return *(const bf16x8*)(ldsB + buf * 16384 + row * 128 +
                            ((((ks << 2) + l16) ^ (row & 7)) << 4));
  };

  stageA(0, 0);
  stageB(0, 0);
  stageA(1, 1);
  stageB(1, 1);
  VMC12;  // 24 outstanding -> retire oldest 12 = all of tile0 (own)
  BARR;

#pragma unroll 1
  for (int t = 0; t < 16; ++t) {
    const int buf = t & 1;
#pragma unroll
    for (int m_ = 0; m_ < 4; ++m_)
#pragma unroll
      for (int ks_ = 0; ks_ < 2; ++ks_)
        aS[m_][ks_] = rdA(buf, m_ * 16 + fr, ks_);
#pragma unroll
    for (int n_ = 0; n_ < 4; ++n_)
#pragma unroll
      for (int ks_ = 0; ks_ < 2; ++ks_)
        bB[n_][ks_] = rdB(buf, wid * 64 + n_ * 16 + fr, ks_);
    LGKM0;
    BARR;
    if (t + 2 < 16) {
      stageA(buf, t + 2);
      stageB(buf, t + 2);
    }
    __builtin_amdgcn_s_setprio(1);
#pragma unroll
    for (int m_ = 0; m_ < 4; ++m_)
#pragma unroll
      for (int n_ = 0; n_ < 4; ++n_)
#pragma unroll
        for (int ks_ = 0; ks_ < 2; ++ks_)
          acc[m_][n_] = __builtin_amdgcn_mfma_f32_16x16x32_bf16(
              aS[m_][ks_], bB[n_][ks_], acc[m_][n_], 0, 0, 0);
    __builtin_amdgcn_s_setprio(0);
    if (t < 15) {
      if (t + 2 < 16) {
        VMC12;
      } else {
        VMC0;
      }
      BARR;
    }
  }

  const int cr = l16 * 4;
#pragma unroll
  for (int nf = 0; nf < 4; ++nf) {
    const int col = n0 + wid * 64 + nf * 16 + fr;  // 0..1023
    const float bval = bias[col];
#pragma unroll
    for (int mf = 0; mf < 4; ++mf) {
      const int row = m0 + mf * 16 + cr;
#pragma unroll
      for (int r = 0; r < 4; ++r)
        out[(size_t)(row + r) * Nd + col] = acc[mf][nf][r] + bval;
    }
  }
}

// ---------------- local attention (thread-per-query, fused QKV in) ---------
#define CHUNK 256
#define TROWS 260

__global__ __launch_bounds__(256) void attn_kernel(
    const bf16_t* __restrict__ QKV, bf16_t* __restrict__ ctx) {
  __shared__ bf16_t ldsK[TROWS * HDIM];
  __shared__ bf16_t ldsV[TROWS * HDIM];

  const int tid = threadIdx.x;
  const int blk = blockIdx.x;
  const int chunk = blk & 7;
  const int bh = blk >> 3;
  const int h = bh & (NHEADS - 1);
  const int b = bh >> 4;
  const int s0 = chunk * CHUNK;

  const bf16_t* Kb = QKV + (size_t)b * S_LEN * QKVN + DMODEL + h * HDIM;
  const bf16_t* Vb = QKV + (size_t)b * S_LEN * QKVN + 2 * DMODEL + h * HDIM;

#pragma unroll
  for (int j = 0; j < 9; ++j) {
    const int i = j * 256 + tid;
    if (i < TROWS * 8) {
      const int tr = i >> 3;
      const int slot = i & 7;
      const int c = slot ^ (tr & 7);
      int gs = s0 - 2 + tr;
      gs = (gs < 0) ? 0 : (gs >= S_LEN ? S_LEN - 1 : gs);
      async16((const char*)(Kb + (size_t)gs * QKVN) + c * 16,
              (char*)ldsK + i * 16);
      async16((const char*)(Vb + (size_t)gs * QKVN) + c * 16,
              (char*)ldsV + i * 16);
    }
  }

  const int s = s0 + tid;
  const bf16_t* Qrow = QKV + ((size_t)(b * S_LEN) + s) * QKVN + h * HDIM;
  bf16x8 q8[8];
#pragma unroll
  for (int c = 0; c < 8; ++c) q8[c] = *(const bf16x8*)(Qrow + c * 8);
  float qf[64];
#pragma unroll
  for (int c = 0; c < 8; ++c)
#pragma unroll
    for (int e = 0; e < 8; ++e) qf[c * 8 + e] = (float)q8[c][e];

  __syncthreads();

  float sc[5];
#pragma unroll
  for (int jj = 0; jj < 5; ++jj) {
    const int tr = tid + jj;
    float d = 0.f;
#pragma unroll
    for (int c = 0; c < 8; ++c) {
      const bf16x8 k8 = *(const bf16x8*)(ldsK + tr * HDIM + (c ^ (tr & 7)) * 8);
#pragma unroll
      for (int e = 0; e < 8; ++e) d += qf[c * 8 + e] * (float)k8[e];
    }
    const int j = s - 2 + jj;
    sc[jj] = (j < 0 || j >= S_LEN) ? -1e30f : d * 0.125f;
  }

  float m = sc[0];
#pragma unroll
  for (int jj = 1; jj < 5; ++jj) m = fmaxf(m, sc[jj]);
  float p[5], l = 0.f;
#pragma unroll
  for (int jj = 0; jj < 5; ++jj) {
    p[jj] = __expf(sc[jj] - m);
    l += p[jj];
  }
  const float inv = 1.0f / l;
#pragma unroll
  for (int jj = 0; jj < 5; ++jj) p[jj] *= inv;

  float o[64];
#pragma unroll
  for (int e = 0; e < 64; ++e) o[e] = 0.f;
#pragma unroll
  for (int jj = 0; jj < 5; ++jj) {
    const int tr = tid + jj;
    const float pj = p[jj];
#pragma unroll
    for (int c = 0; c < 8; ++c) {
      const bf16x8 v8 = *(const bf16x8*)(ldsV + tr * HDIM + (c ^ (tr & 7)) * 8);
#pragma unroll
      for (int e = 0; e < 8; ++e) o[c * 8 + e] += pj * (float)v8[e];
    }
  }

  bf16_t* Crow = (bf16_t*)ctx + ((size_t)(b * S_LEN) + s) * DMODEL + h * HDIM;
#pragma unroll
  for (int c = 0; c < 8; ++c) {
    bf16x8 ov;
#pragma unroll
    for (int e = 0; e < 8; ++e) ov[e] = (bf16_t)o[c * 8 + e];
    *(bf16x8*)(Crow + c * 8) = ov;
  }
}

extern "C" void kernel_launch(void* const* d_in, const int* in_sizes, int n_in,
                              void* d_out, int out_size, void* d_ws,
                              size_t ws_size, hipStream_t stream) {
  const float* x = (const float*)d_in[0];
  const float* Wq = (const float*)d_in[1];
  const float* bq = (const float*)d_in[2];
  const float* Wk = (const float*)d_in[3];
  const float* bk = (const float*)d_in[4];
  const float* Wv = (const float*)d_in[5];
  const float* bv = (const float*)d_in[6];
  const float* Wo = (const float*)d_in[7];
  const float* bo = (const float*)d_in[8];
  float* out = (float*)d_out;

  const size_t mat = (size_t)BROWS * DMODEL;
  const size_t wmat = (size_t)DMODEL * DMODEL;
  bf16_t* xb = (bf16_t*)d_ws;   // [xb | Wqkv | Wob] contiguous (cvt dst)
  bf16_t* Wqkv = xb + mat;      // fused [3072][1024]
  bf16_t* Wob = Wqkv + 3 * wmat;
  bf16_t* QKV = Wob + wmat;     // fused [4096][3072]
  bf16_t* ctx = QKV + 3 * mat;

  cvt_all_kernel<<<8192, 256, 0, stream>>>(x, Wq, Wk, Wv, Wo, xb);
  // QKV: 64x192 tiles, BK=32 -> grid 64x16 = 1024 blocks = 4 blocks/CU
  gemm_qkv_kernel<<<dim3(64, 16), 128, 0, stream>>>(xb, Wqkv, bq, bk, bv,
                                                    QKV);
  attn_kernel<<<256, 256, 0, stream>>>(QKV, ctx);
  // O: 64x128 tiles -> grid 64x8 = 512 blocks = 2 blocks/CU
  gemm_o_kernel<<<dim3(64, 8), 128, 0, stream>>>(ctx, Wob, bo, out);
}

// Round 18
// 75.908 us; speedup vs baseline: 1.0749x; 1.0749x over previous
//
#include <hip/hip_runtime.h>
#include <hip/hip_bf16.h>

typedef __bf16 bf16_t;
typedef __bf16 bf16x4 __attribute__((ext_vector_type(4)));
typedef __bf16 bf16x8 __attribute__((ext_vector_type(8)));
typedef float f32x4 __attribute__((ext_vector_type(4)));

#define S_LEN 2048
#define DMODEL 1024
#define NHEADS 16
#define HDIM 64
#define BROWS 4096   // B * S
#define QKVN 3072    // fused QKV output width

__device__ __forceinline__ void async16(const void* g, void* l) {
  __builtin_amdgcn_global_load_lds(
      (const __attribute__((address_space(1))) void*)g,
      (__attribute__((address_space(3))) void*)l, 16, 0, 0);
}

// ------------- fused f32 -> bf16 conversion (x, Wq, Wk, Wv, Wo) -------------
__global__ __launch_bounds__(256) void cvt_all_kernel(
    const float* __restrict__ x, const float* __restrict__ Wq,
    const float* __restrict__ Wk, const float* __restrict__ Wv,
    const float* __restrict__ Wo, bf16_t* __restrict__ dst) {
  const int i = blockIdx.x * 256 + threadIdx.x;  // float4 index
  constexpr int XN4 = (BROWS * DMODEL) / 4;      // 1048576
  constexpr int WN4 = (DMODEL * DMODEL) / 4;     // 262144
  const float* src;
  size_t off;
  if (i < XN4) {
    src = x;
    off = (size_t)i;
  } else {
    const int wi = i - XN4;
    const int w = wi >> 18;
    off = (size_t)(wi & (WN4 - 1));
    src = (w == 0) ? Wq : (w == 1) ? Wk : (w == 2) ? Wv : Wo;
  }
  const float4 v = *(const float4*)(src + off * 4);
  bf16x4 o;
  o[0] = (bf16_t)v.x;
  o[1] = (bf16_t)v.y;
  o[2] = (bf16_t)v.z;
  o[3] = (bf16_t)v.w;
  *(bf16x4*)(dst + (size_t)i * 4) = o;
}

#define BARR __builtin_amdgcn_s_barrier()
#define LGKM0 asm volatile("s_waitcnt lgkmcnt(0)" ::: "memory")
#define VMC12 asm volatile("s_waitcnt vmcnt(12)" ::: "memory")
#define VMC0 asm volatile("s_waitcnt vmcnt(0)" ::: "memory")

// ====== 64x128 GEMM (QKV): r16-O template verbatim, 3 blocks/CU =============
// Round-18: r17's 64B-row swizzle was a 4-way bank conflict (2.6M measured)
// -- reverted.  This is the VERIFIED r16 O-proj body (128B rows, proven
// slot^(r&7) swizzle, BK=64, 12 stage-instr/tile, VMC12/VMC0 gates) with
// only the epilogue changed: bf16 out at stride QKVN + bias select col>>10.
// LDS 48KB -> 3 blocks/CU resident; grid 64x24 = 1536 = 6/CU scheduled.
__global__ __launch_bounds__(128) void gemm_qkv_kernel(
    const bf16_t* __restrict__ A, const bf16_t* __restrict__ W,
    const float* __restrict__ bq, const float* __restrict__ bk,
    const float* __restrict__ bv, bf16_t* __restrict__ C) {
  constexpr int Kd = 1024;
  __shared__ char lds[49152];  // A: 2buf*8KB = 16KB, B: 2buf*16KB = 32KB
  char* ldsA = lds;            // + buf*8192
  char* ldsB = lds + 16384;    // + buf*16384

  const int m0 = blockIdx.x * 64;
  const int n0 = blockIdx.y * 128;

  const int tid = threadIdx.x;  // 0..127
  const int lane = tid & 63;
  const int wid = tid >> 6;  // 0..1 (64-col halves)
  const int fr = lane & 15;
  const int l16 = lane >> 4;

  f32x4 acc[4][4] = {};
  bf16x8 aS[4][2], bB[4][2];

  auto stageA = [&](int buf, int kt) {
#pragma unroll
    for (int l = 0; l < 4; ++l) {
      const int idx = l * 128 + tid;
      const int r = idx >> 3;  // 0..63
      const int slot = idx & 7;
      async16((const char*)(A + (size_t)(m0 + r) * Kd + kt * 64 +
                            ((slot ^ (r & 7)) << 3)),
              ldsA + buf * 8192 + r * 128 + slot * 16);
    }
  };
  auto stageB = [&](int buf, int kt) {
#pragma unroll
    for (int l = 0; l < 8; ++l) {
      const int idx = l * 128 + tid;
      const int r = idx >> 3;  // 0..127
      const int slot = idx & 7;
      async16((const char*)(W + (size_t)(n0 + r) * Kd + kt * 64 +
                            ((slot ^ (r & 7)) << 3)),
              ldsB + buf * 16384 + r * 128 + slot * 16);
    }
  };

  auto rdA = [&](int buf, int row, int ks) -> bf16x8 {
    return *(const bf16x8*)(ldsA + buf * 8192 + row * 128 +
                            ((((ks << 2) + l16) ^ (row & 7)) << 4));
  };
  auto rdB = [&](int buf, int row, int ks) -> bf16x8 {
    return *(const bf16x8*)(ldsB + buf * 16384 + row * 128 +
                            ((((ks << 2) + l16) ^ (row & 7)) << 4));
  };

  stageA(0, 0);
  stageB(0, 0);
  stageA(1, 1);
  stageB(1, 1);
  VMC12;  // 24 outstanding -> retire oldest 12 = all of tile0 (own)
  BARR;   // certify tile0 across both waves

#pragma unroll 1
  for (int t = 0; t < 16; ++t) {
    const int buf = t & 1;
#pragma unroll
    for (int m_ = 0; m_ < 4; ++m_)
#pragma unroll
      for (int ks_ = 0; ks_ < 2; ++ks_)
        aS[m_][ks_] = rdA(buf, m_ * 16 + fr, ks_);
#pragma unroll
    for (int n_ = 0; n_ < 4; ++n_)
#pragma unroll
      for (int ks_ = 0; ks_ < 2; ++ks_)
        bB[n_][ks_] = rdB(buf, wid * 64 + n_ * 16 + fr, ks_);
    LGKM0;  // own reads retired...
    BARR;   // ...all waves' reads retired -> buf safe to overwrite
    if (t + 2 < 16) {
      stageA(buf, t + 2);
      stageB(buf, t + 2);
    }
    __builtin_amdgcn_s_setprio(1);
#pragma unroll
    for (int m_ = 0; m_ < 4; ++m_)
#pragma unroll
      for (int n_ = 0; n_ < 4; ++n_)
#pragma unroll
        for (int ks_ = 0; ks_ < 2; ++ks_)
          acc[m_][n_] = __builtin_amdgcn_mfma_f32_16x16x32_bf16(
              aS[m_][ks_], bB[n_][ks_], acc[m_][n_], 0, 0, 0);
    __builtin_amdgcn_s_setprio(0);
    if (t < 15) {
      if (t + 2 < 16) {
        VMC12;  // outstanding t+1's 12 + t+2's 12 -> retire t+1's
      } else {
        VMC0;   // t=14: only t15's 12 outstanding
      }
      BARR;
    }
  }

  // epilogue: bf16 out, stride QKVN, bias select by col>>10
  const int cr = l16 * 4;
#pragma unroll
  for (int nf = 0; nf < 4; ++nf) {
    const int col = n0 + wid * 64 + nf * 16 + fr;  // 0..3071
    const int mat = col >> 10;
    const float* bp = (mat == 0) ? bq : (mat == 1) ? bk : bv;
    const float bval = bp[col & 1023];
#pragma unroll
    for (int mf = 0; mf < 4; ++mf) {
      const int row = m0 + mf * 16 + cr;
#pragma unroll
      for (int r = 0; r < 4; ++r)
        C[(size_t)(row + r) * QKVN + col] = (bf16_t)(acc[mf][nf][r] + bval);
    }
  }
}

// ====== 64x128 GEMM (O-proj): r16 verified, 2 waves, 2 blocks/CU ============
__global__ __launch_bounds__(128) void gemm_o_kernel(
    const bf16_t* __restrict__ A, const bf16_t* __restrict__ W,
    const float* __restrict__ bias, float* __restrict__ out) {
  constexpr int Kd = 1024, Nd = 1024;
  __shared__ char lds[49152];
  char* ldsA = lds;
  char* ldsB = lds + 16384;

  const int m0 = blockIdx.x * 64;
  const int n0 = blockIdx.y * 128;

  const int tid = threadIdx.x;
  const int lane = tid & 63;
  const int wid = tid >> 6;
  const int fr = lane & 15;
  const int l16 = lane >> 4;

  f32x4 acc[4][4] = {};
  bf16x8 aS[4][2], bB[4][2];

  auto stageA = [&](int buf, int kt) {
#pragma unroll
    for (int l = 0; l < 4; ++l) {
      const int idx = l * 128 + tid;
      const int r = idx >> 3;
      const int slot = idx & 7;
      async16((const char*)(A + (size_t)(m0 + r) * Kd + kt * 64 +
                            ((slot ^ (r & 7)) << 3)),
              ldsA + buf * 8192 + r * 128 + slot * 16);
    }
  };
  auto stageB = [&](int buf, int kt) {
#pragma unroll
    for (int l = 0; l < 8; ++l) {
      const int idx = l * 128 + tid;
      const int r = idx >> 3;
      const int slot = idx & 7;
      async16((const char*)(W + (size_t)(n0 + r) * Kd + kt * 64 +
                            ((slot ^ (r & 7)) << 3)),
              ldsB + buf * 16384 + r * 128 + slot * 16);
    }
  };

  auto rdA = [&](int buf, int row, int ks) -> bf16x8 {
    return *(const bf16x8*)(ldsA + buf * 8192 + row * 128 +
                            ((((ks << 2) + l16) ^ (row & 7)) << 4));
  };
  auto rdB = [&](int buf, int row, int ks) -> bf16x8 {
    return *(const bf16x8*)(ldsB + buf * 16384 + row * 128 +
                            ((((ks << 2) + l16) ^ (row & 7)) << 4));
  };

  stageA(0, 0);
  stageB(0, 0);
  stageA(1, 1);
  stageB(1, 1);
  VMC12;
  BARR;

#pragma unroll 1
  for (int t = 0; t < 16; ++t) {
    const int buf = t & 1;
#pragma unroll
    for (int m_ = 0; m_ < 4; ++m_)
#pragma unroll
      for (int ks_ = 0; ks_ < 2; ++ks_)
        aS[m_][ks_] = rdA(buf, m_ * 16 + fr, ks_);
#pragma unroll
    for (int n_ = 0; n_ < 4; ++n_)
#pragma unroll
      for (int ks_ = 0; ks_ < 2; ++ks_)
        bB[n_][ks_] = rdB(buf, wid * 64 + n_ * 16 + fr, ks_);
    LGKM0;
    BARR;
    if (t + 2 < 16) {
      stageA(buf, t + 2);
      stageB(buf, t + 2);
    }
    __builtin_amdgcn_s_setprio(1);
#pragma unroll
    for (int m_ = 0; m_ < 4; ++m_)
#pragma unroll
      for (int n_ = 0; n_ < 4; ++n_)
#pragma unroll
        for (int ks_ = 0; ks_ < 2; ++ks_)
          acc[m_][n_] = __builtin_amdgcn_mfma_f32_16x16x32_bf16(
              aS[m_][ks_], bB[n_][ks_], acc[m_][n_], 0, 0, 0);
    __builtin_amdgcn_s_setprio(0);
    if (t < 15) {
      if (t + 2 < 16) {
        VMC12;
      } else {
        VMC0;
      }
      BARR;
    }
  }

  const int cr = l16 * 4;
#pragma unroll
  for (int nf = 0; nf < 4; ++nf) {
    const int col = n0 + wid * 64 + nf * 16 + fr;
    const float bval = bias[col];
#pragma unroll
    for (int mf = 0; mf < 4; ++mf) {
      const int row = m0 + mf * 16 + cr;
#pragma unroll
      for (int r = 0; r < 4; ++r)
        out[(size_t)(row + r) * Nd + col] = acc[mf][nf][r] + bval;
    }
  }
}

// ---------------- local attention (thread-per-query, fused QKV in) ---------
#define CHUNK 256
#define TROWS 260

__global__ __launch_bounds__(256) void attn_kernel(
    const bf16_t* __restrict__ QKV, bf16_t* __restrict__ ctx) {
  __shared__ bf16_t ldsK[TROWS * HDIM];
  __shared__ bf16_t ldsV[TROWS * HDIM];

  const int tid = threadIdx.x;
  const int blk = blockIdx.x;
  const int chunk = blk & 7;
  const int bh = blk >> 3;
  const int h = bh & (NHEADS - 1);
  const int b = bh >> 4;
  const int s0 = chunk * CHUNK;

  const bf16_t* Kb = QKV + (size_t)b * S_LEN * QKVN + DMODEL + h * HDIM;
  const bf16_t* Vb = QKV + (size_t)b * S_LEN * QKVN + 2 * DMODEL + h * HDIM;

#pragma unroll
  for (int j = 0; j < 9; ++j) {
    const int i = j * 256 + tid;
    if (i < TROWS * 8) {
      const int tr = i >> 3;
      const int slot = i & 7;
      const int c = slot ^ (tr & 7);
      int gs = s0 - 2 + tr;
      gs = (gs < 0) ? 0 : (gs >= S_LEN ? S_LEN - 1 : gs);
      async16((const char*)(Kb + (size_t)gs * QKVN) + c * 16,
              (char*)ldsK + i * 16);
      async16((const char*)(Vb + (size_t)gs * QKVN) + c * 16,
              (char*)ldsV + i * 16);
    }
  }

  const int s = s0 + tid;
  const bf16_t* Qrow = QKV + ((size_t)(b * S_LEN) + s) * QKVN + h * HDIM;
  bf16x8 q8[8];
#pragma unroll
  for (int c = 0; c < 8; ++c) q8[c] = *(const bf16x8*)(Qrow + c * 8);
  float qf[64];
#pragma unroll
  for (int c = 0; c < 8; ++c)
#pragma unroll
    for (int e = 0; e < 8; ++e) qf[c * 8 + e] = (float)q8[c][e];

  __syncthreads();

  float sc[5];
#pragma unroll
  for (int jj = 0; jj < 5; ++jj) {
    const int tr = tid + jj;
    float d = 0.f;
#pragma unroll
    for (int c = 0; c < 8; ++c) {
      const bf16x8 k8 = *(const bf16x8*)(ldsK + tr * HDIM + (c ^ (tr & 7)) * 8);
#pragma unroll
      for (int e = 0; e < 8; ++e) d += qf[c * 8 + e] * (float)k8[e];
    }
    const int j = s - 2 + jj;
    sc[jj] = (j < 0 || j >= S_LEN) ? -1e30f : d * 0.125f;
  }

  float m = sc[0];
#pragma unroll
  for (int jj = 1; jj < 5; ++jj) m = fmaxf(m, sc[jj]);
  float p[5], l = 0.f;
#pragma unroll
  for (int jj = 0; jj < 5; ++jj) {
    p[jj] = __expf(sc[jj] - m);
    l += p[jj];
  }
  const float inv = 1.0f / l;
#pragma unroll
  for (int jj = 0; jj < 5; ++jj) p[jj] *= inv;

  float o[64];
#pragma unroll
  for (int e = 0; e < 64; ++e) o[e] = 0.f;
#pragma unroll
  for (int jj = 0; jj < 5; ++jj) {
    const int tr = tid + jj;
    const float pj = p[jj];
#pragma unroll
    for (int c = 0; c < 8; ++c) {
      const bf16x8 v8 = *(const bf16x8*)(ldsV + tr * HDIM + (c ^ (tr & 7)) * 8);
#pragma unroll
      for (int e = 0; e < 8; ++e) o[c * 8 + e] += pj * (float)v8[e];
    }
  }

  bf16_t* Crow = (bf16_t*)ctx + ((size_t)(b * S_LEN) + s) * DMODEL + h * HDIM;
#pragma unroll
  for (int c = 0; c < 8; ++c) {
    bf16x8 ov;
#pragma unroll
    for (int e = 0; e < 8; ++e) ov[e] = (bf16_t)o[c * 8 + e];
    *(bf16x8*)(Crow + c * 8) = ov;
  }
}

extern "C" void kernel_launch(void* const* d_in, const int* in_sizes, int n_in,
                              void* d_out, int out_size, void* d_ws,
                              size_t ws_size, hipStream_t stream) {
  const float* x = (const float*)d_in[0];
  const float* Wq = (const float*)d_in[1];
  const float* bq = (const float*)d_in[2];
  const float* Wk = (const float*)d_in[3];
  const float* bk = (const float*)d_in[4];
  const float* Wv = (const float*)d_in[5];
  const float* bv = (const float*)d_in[6];
  const float* Wo = (const float*)d_in[7];
  const float* bo = (const float*)d_in[8];
  float* out = (float*)d_out;

  const size_t mat = (size_t)BROWS * DMODEL;
  const size_t wmat = (size_t)DMODEL * DMODEL;
  bf16_t* xb = (bf16_t*)d_ws;   // [xb | Wqkv | Wob] contiguous (cvt dst)
  bf16_t* Wqkv = xb + mat;      // fused [3072][1024]
  bf16_t* Wob = Wqkv + 3 * wmat;
  bf16_t* QKV = Wob + wmat;     // fused [4096][3072]
  bf16_t* ctx = QKV + 3 * mat;

  cvt_all_kernel<<<8192, 256, 0, stream>>>(x, Wq, Wk, Wv, Wo, xb);
  // QKV: 64x128 tiles (r16-O template) -> grid 64x24 = 1536 = 3 blocks/CU res
  gemm_qkv_kernel<<<dim3(64, 24), 128, 0, stream>>>(xb, Wqkv, bq, bk, bv,
                                                    QKV);
  attn_kernel<<<256, 256, 0, stream>>>(QKV, ctx);
  // O: 64x128 tiles -> grid 64x8 = 512 blocks = 2 blocks/CU
  gemm_o_kernel<<<dim3(64, 8), 128, 0, stream>>>(ctx, Wob, bo, out);
}

// Round 19
// 68.914 us; speedup vs baseline: 1.1840x; 1.1015x over previous
//
#include <hip/hip_runtime.h>
#include <hip/hip_bf16.h>

typedef __bf16 bf16_t;
typedef __bf16 bf16x4 __attribute__((ext_vector_type(4)));
typedef __bf16 bf16x8 __attribute__((ext_vector_type(8)));
typedef float f32x4 __attribute__((ext_vector_type(4)));

#define S_LEN 2048
#define DMODEL 1024
#define NHEADS 16
#define HDIM 64
#define BROWS 4096   // B * S
#define QKVN 3072    // fused QKV output width

__device__ __forceinline__ void async16(const void* g, void* l) {
  __builtin_amdgcn_global_load_lds(
      (const __attribute__((address_space(1))) void*)g,
      (__attribute__((address_space(3))) void*)l, 16, 0, 0);
}

// ------------- fused f32 -> bf16 conversion (x, Wq, Wk, Wv, Wo) -------------
__global__ __launch_bounds__(256) void cvt_all_kernel(
    const float* __restrict__ x, const float* __restrict__ Wq,
    const float* __restrict__ Wk, const float* __restrict__ Wv,
    const float* __restrict__ Wo, bf16_t* __restrict__ dst) {
  const int i = blockIdx.x * 256 + threadIdx.x;  // float4 index
  constexpr int XN4 = (BROWS * DMODEL) / 4;      // 1048576
  constexpr int WN4 = (DMODEL * DMODEL) / 4;     // 262144
  const float* src;
  size_t off;
  if (i < XN4) {
    src = x;
    off = (size_t)i;
  } else {
    const int wi = i - XN4;
    const int w = wi >> 18;
    off = (size_t)(wi & (WN4 - 1));
    src = (w == 0) ? Wq : (w == 1) ? Wk : (w == 2) ? Wv : Wo;
  }
  const float4 v = *(const float4*)(src + off * 4);
  bf16x4 o;
  o[0] = (bf16_t)v.x;
  o[1] = (bf16_t)v.y;
  o[2] = (bf16_t)v.z;
  o[3] = (bf16_t)v.w;
  *(bf16x4*)(dst + (size_t)i * 4) = o;
}

#define BARR __builtin_amdgcn_s_barrier()
#define LGKM0 asm volatile("s_waitcnt lgkmcnt(0)" ::: "memory")
#define VMC10 asm volatile("s_waitcnt vmcnt(10)" ::: "memory")
#define VMC12 asm volatile("s_waitcnt vmcnt(12)" ::: "memory")
#define VMC0 asm volatile("s_waitcnt vmcnt(0)" ::: "memory")

// ========== 128x192 GEMM (QKV): r15 verified + T1 XCD swizzle ===============
// (2 blocks/CU, 4 waves; reads -> LGKM0 -> BARR#1 -> stage(t+2) -> MFMA ->
//  VMC(<=10) -> BARR#2; swizzle slot^(r&7); bijective XCD remap 512=8*64.)
__global__ __launch_bounds__(256, 2) void gemm_qkv_kernel(
    const bf16_t* __restrict__ A, const bf16_t* __restrict__ W,
    const float* __restrict__ bq, const float* __restrict__ bk,
    const float* __restrict__ bv, bf16_t* __restrict__ C) {
  constexpr int Kd = 1024;
  __shared__ char lds[81920];  // A: 2buf*16KB, B: 2buf*24KB = 80KB
  char* ldsA = lds;            // + buf*16384
  char* ldsB = lds + 32768;    // + buf*24576

  // T1: XCD-aware bijective remap (512 blocks = 8 XCD chunks of 64)
  const int lin = blockIdx.y * 32 + blockIdx.x;
  const int swz = ((lin & 7) << 6) | (lin >> 3);
  const int m0 = (swz & 31) * 128;
  const int n0 = (swz >> 5) * 192;

  const int tid = threadIdx.x;
  const int lane = tid & 63;
  const int wid = tid >> 6;   // 0..3
  const int wr = wid >> 1;    // 0..1 (64 rows each)
  const int wc = wid & 1;     // 0..1 (96 cols each)
  const int fr = lane & 15;
  const int l16 = lane >> 4;

  f32x4 acc[4][6] = {};
  bf16x8 aS[4][2], bB[6][2];

  auto stageA = [&](int buf, int kt) {
#pragma unroll
    for (int l = 0; l < 4; ++l) {
      const int idx = l * 256 + tid;
      const int r = idx >> 3;  // 0..127
      const int slot = idx & 7;
      async16((const char*)(A + (size_t)(m0 + r) * Kd + kt * 64 +
                            ((slot ^ (r & 7)) << 3)),
              ldsA + buf * 16384 + r * 128 + slot * 16);
    }
  };
  auto stageB = [&](int buf, int kt) {
#pragma unroll
    for (int l = 0; l < 6; ++l) {
      const int idx = l * 256 + tid;
      const int r = idx >> 3;  // 0..191
      const int slot = idx & 7;
      async16((const char*)(W + (size_t)(n0 + r) * Kd + kt * 64 +
                            ((slot ^ (r & 7)) << 3)),
              ldsB + buf * 24576 + r * 128 + slot * 16);
    }
  };

  auto rdA = [&](int buf, int row, int ks) -> bf16x8 {
    return *(const bf16x8*)(ldsA + buf * 16384 + row * 128 +
                            ((((ks << 2) + l16) ^ (row & 7)) << 4));
  };
  auto rdB = [&](int buf, int row, int ks) -> bf16x8 {
    return *(const bf16x8*)(ldsB + buf * 24576 + row * 128 +
                            ((((ks << 2) + l16) ^ (row & 7)) << 4));
  };

  stageA(0, 0);
  stageB(0, 0);
  stageA(1, 1);
  stageB(1, 1);
  VMC10;  // 20 outstanding -> retire oldest 10 = all of tile0 (own)
  BARR;   // barrier-release certifies tile0 across all waves

#pragma unroll 1
  for (int t = 0; t < 16; ++t) {
    const int buf = t & 1;
#pragma unroll
    for (int m_ = 0; m_ < 4; ++m_)
#pragma unroll
      for (int ks_ = 0; ks_ < 2; ++ks_)
        aS[m_][ks_] = rdA(buf, wr * 64 + m_ * 16 + fr, ks_);
#pragma unroll
    for (int n_ = 0; n_ < 6; ++n_)
#pragma unroll
      for (int ks_ = 0; ks_ < 2; ++ks_)
        bB[n_][ks_] = rdB(buf, wc * 96 + n_ * 16 + fr, ks_);
    LGKM0;
    BARR;
    if (t + 2 < 16) {
      stageA(buf, t + 2);
      stageB(buf, t + 2);
    }
    __builtin_amdgcn_s_setprio(1);
#pragma unroll
    for (int m_ = 0; m_ < 4; ++m_)
#pragma unroll
      for (int n_ = 0; n_ < 6; ++n_)
#pragma unroll
        for (int ks_ = 0; ks_ < 2; ++ks_)
          acc[m_][n_] = __builtin_amdgcn_mfma_f32_16x16x32_bf16(
              aS[m_][ks_], bB[n_][ks_], acc[m_][n_], 0, 0, 0);
    __builtin_amdgcn_s_setprio(0);
    if (t < 15) {
      if (t + 2 < 16) {
        VMC10;
      } else {
        VMC0;
      }
      BARR;
    }
  }

  const int cr = l16 * 4;
#pragma unroll
  for (int nf = 0; nf < 6; ++nf) {
    const int col = n0 + wc * 96 + nf * 16 + fr;  // 0..3071
    const int mat = col >> 10;
    const float* bp = (mat == 0) ? bq : (mat == 1) ? bk : bv;
    const float bval = bp[col & 1023];
#pragma unroll
    for (int mf = 0; mf < 4; ++mf) {
      const int row = m0 + wr * 64 + mf * 16 + cr;
#pragma unroll
      for (int r = 0; r < 4; ++r)
        C[(size_t)(row + r) * QKVN + col] = (bf16_t)(acc[mf][nf][r] + bval);
    }
  }
}

// ====== 64x128 GEMM (O-proj): r16 verified + T1 XCD swizzle =================
__global__ __launch_bounds__(128) void gemm_o_kernel(
    const bf16_t* __restrict__ A, const bf16_t* __restrict__ W,
    const float* __restrict__ bias, float* __restrict__ out) {
  constexpr int Kd = 1024, Nd = 1024;
  __shared__ char lds[49152];
  char* ldsA = lds;
  char* ldsB = lds + 16384;

  // T1: XCD-aware bijective remap (512 blocks = 8 XCD chunks of 64)
  const int lin = blockIdx.y * 64 + blockIdx.x;
  const int swz = ((lin & 7) << 6) | (lin >> 3);
  const int m0 = (swz & 63) * 64;
  const int n0 = (swz >> 6) * 128;

  const int tid = threadIdx.x;
  const int lane = tid & 63;
  const int wid = tid >> 6;
  const int fr = lane & 15;
  const int l16 = lane >> 4;

  f32x4 acc[4][4] = {};
  bf16x8 aS[4][2], bB[4][2];

  auto stageA = [&](int buf, int kt) {
#pragma unroll
    for (int l = 0; l < 4; ++l) {
      const int idx = l * 128 + tid;
      const int r = idx >> 3;
      const int slot = idx & 7;
      async16((const char*)(A + (size_t)(m0 + r) * Kd + kt * 64 +
                            ((slot ^ (r & 7)) << 3)),
              ldsA + buf * 8192 + r * 128 + slot * 16);
    }
  };
  auto stageB = [&](int buf, int kt) {
#pragma unroll
    for (int l = 0; l < 8; ++l) {
      const int idx = l * 128 + tid;
      const int r = idx >> 3;
      const int slot = idx & 7;
      async16((const char*)(W + (size_t)(n0 + r) * Kd + kt * 64 +
                            ((slot ^ (r & 7)) << 3)),
              ldsB + buf * 16384 + r * 128 + slot * 16);
    }
  };

  auto rdA = [&](int buf, int row, int ks) -> bf16x8 {
    return *(const bf16x8*)(ldsA + buf * 8192 + row * 128 +
                            ((((ks << 2) + l16) ^ (row & 7)) << 4));
  };
  auto rdB = [&](int buf, int row, int ks) -> bf16x8 {
    return *(const bf16x8*)(ldsB + buf * 16384 + row * 128 +
                            ((((ks << 2) + l16) ^ (row & 7)) << 4));
  };

  stageA(0, 0);
  stageB(0, 0);
  stageA(1, 1);
  stageB(1, 1);
  VMC12;
  BARR;

#pragma unroll 1
  for (int t = 0; t < 16; ++t) {
    const int buf = t & 1;
#pragma unroll
    for (int m_ = 0; m_ < 4; ++m_)
#pragma unroll
      for (int ks_ = 0; ks_ < 2; ++ks_)
        aS[m_][ks_] = rdA(buf, m_ * 16 + fr, ks_);
#pragma unroll
    for (int n_ = 0; n_ < 4; ++n_)
#pragma unroll
      for (int ks_ = 0; ks_ < 2; ++ks_)
        bB[n_][ks_] = rdB(buf, wid * 64 + n_ * 16 + fr, ks_);
    LGKM0;
    BARR;
    if (t + 2 < 16) {
      stageA(buf, t + 2);
      stageB(buf, t + 2);
    }
    __builtin_amdgcn_s_setprio(1);
#pragma unroll
    for (int m_ = 0; m_ < 4; ++m_)
#pragma unroll
      for (int n_ = 0; n_ < 4; ++n_)
#pragma unroll
        for (int ks_ = 0; ks_ < 2; ++ks_)
          acc[m_][n_] = __builtin_amdgcn_mfma_f32_16x16x32_bf16(
              aS[m_][ks_], bB[n_][ks_], acc[m_][n_], 0, 0, 0);
    __builtin_amdgcn_s_setprio(0);
    if (t < 15) {
      if (t + 2 < 16) {
        VMC12;
      } else {
        VMC0;
      }
      BARR;
    }
  }

  const int cr = l16 * 4;
#pragma unroll
  for (int nf = 0; nf < 4; ++nf) {
    const int col = n0 + wid * 64 + nf * 16 + fr;
    const float bval = bias[col];
#pragma unroll
    for (int mf = 0; mf < 4; ++mf) {
      const int row = m0 + mf * 16 + cr;
#pragma unroll
      for (int r = 0; r < 4; ++r)
        out[(size_t)(row + r) * Nd + col] = acc[mf][nf][r] + bval;
    }
  }
}

// ------- local attention (thread-per-query, CHUNK=128, 2 blocks/CU) --------
#define CHUNK 128
#define TROWS 132  // CHUNK + WINDOW - 1

__global__ __launch_bounds__(128) void attn_kernel(
    const bf16_t* __restrict__ QKV, bf16_t* __restrict__ ctx) {
  __shared__ bf16_t ldsK[TROWS * HDIM];
  __shared__ bf16_t ldsV[TROWS * HDIM];

  const int tid = threadIdx.x;   // 0..127
  const int blk = blockIdx.x;    // 0..511
  const int chunk = blk & 15;    // 16 chunks of 128 queries
  const int bh = blk >> 4;       // 0..31
  const int h = bh & (NHEADS - 1);
  const int b = bh >> 4;
  const int s0 = chunk * CHUNK;

  const bf16_t* Kb = QKV + (size_t)b * S_LEN * QKVN + DMODEL + h * HDIM;
  const bf16_t* Vb = QKV + (size_t)b * S_LEN * QKVN + 2 * DMODEL + h * HDIM;

#pragma unroll
  for (int j = 0; j < 9; ++j) {
    const int i = j * 128 + tid;  // 16B chunk index, TROWS*8 = 1056 total
    if (i < TROWS * 8) {
      const int tr = i >> 3;
      const int slot = i & 7;
      const int c = slot ^ (tr & 7);
      int gs = s0 - 2 + tr;
      gs = (gs < 0) ? 0 : (gs >= S_LEN ? S_LEN - 1 : gs);
      async16((const char*)(Kb + (size_t)gs * QKVN) + c * 16,
              (char*)ldsK + i * 16);
      async16((const char*)(Vb + (size_t)gs * QKVN) + c * 16,
              (char*)ldsV + i * 16);
    }
  }

  const int s = s0 + tid;
  const bf16_t* Qrow = QKV + ((size_t)(b * S_LEN) + s) * QKVN + h * HDIM;
  bf16x8 q8[8];
#pragma unroll
  for (int c = 0; c < 8; ++c) q8[c] = *(const bf16x8*)(Qrow + c * 8);
  float qf[64];
#pragma unroll
  for (int c = 0; c < 8; ++c)
#pragma unroll
    for (int e = 0; e < 8; ++e) qf[c * 8 + e] = (float)q8[c][e];

  __syncthreads();

  float sc[5];
#pragma unroll
  for (int jj = 0; jj < 5; ++jj) {
    const int tr = tid + jj;  // <= 131
    float d = 0.f;
#pragma unroll
    for (int c = 0; c < 8; ++c) {
      const bf16x8 k8 = *(const bf16x8*)(ldsK + tr * HDIM + (c ^ (tr & 7)) * 8);
#pragma unroll
      for (int e = 0; e < 8; ++e) d += qf[c * 8 + e] * (float)k8[e];
    }
    const int j = s - 2 + jj;
    sc[jj] = (j < 0 || j >= S_LEN) ? -1e30f : d * 0.125f;
  }

  float m = sc[0];
#pragma unroll
  for (int jj = 1; jj < 5; ++jj) m = fmaxf(m, sc[jj]);
  float p[5], l = 0.f;
#pragma unroll
  for (int jj = 0; jj < 5; ++jj) {
    p[jj] = __expf(sc[jj] - m);
    l += p[jj];
  }
  const float inv = 1.0f / l;
#pragma unroll
  for (int jj = 0; jj < 5; ++jj) p[jj] *= inv;

  float o[64];
#pragma unroll
  for (int e = 0; e < 64; ++e) o[e] = 0.f;
#pragma unroll
  for (int jj = 0; jj < 5; ++jj) {
    const int tr = tid + jj;
    const float pj = p[jj];
#pragma unroll
    for (int c = 0; c < 8; ++c) {
      const bf16x8 v8 = *(const bf16x8*)(ldsV + tr * HDIM + (c ^ (tr & 7)) * 8);
#pragma unroll
      for (int e = 0; e < 8; ++e) o[c * 8 + e] += pj * (float)v8[e];
    }
  }

  bf16_t* Crow = (bf16_t*)ctx + ((size_t)(b * S_LEN) + s) * DMODEL + h * HDIM;
#pragma unroll
  for (int c = 0; c < 8; ++c) {
    bf16x8 ov;
#pragma unroll
    for (int e = 0; e < 8; ++e) ov[e] = (bf16_t)o[c * 8 + e];
    *(bf16x8*)(Crow + c * 8) = ov;
  }
}

extern "C" void kernel_launch(void* const* d_in, const int* in_sizes, int n_in,
                              void* d_out, int out_size, void* d_ws,
                              size_t ws_size, hipStream_t stream) {
  const float* x = (const float*)d_in[0];
  const float* Wq = (const float*)d_in[1];
  const float* bq = (const float*)d_in[2];
  const float* Wk = (const float*)d_in[3];
  const float* bk = (const float*)d_in[4];
  const float* Wv = (const float*)d_in[5];
  const float* bv = (const float*)d_in[6];
  const float* Wo = (const float*)d_in[7];
  const float* bo = (const float*)d_in[8];
  float* out = (float*)d_out;

  const size_t mat = (size_t)BROWS * DMODEL;
  const size_t wmat = (size_t)DMODEL * DMODEL;
  bf16_t* xb = (bf16_t*)d_ws;   // [xb | Wqkv | Wob] contiguous (cvt dst)
  bf16_t* Wqkv = xb + mat;      // fused [3072][1024]
  bf16_t* Wob = Wqkv + 3 * wmat;
  bf16_t* QKV = Wob + wmat;     // fused [4096][3072]
  bf16_t* ctx = QKV + 3 * mat;

  cvt_all_kernel<<<8192, 256, 0, stream>>>(x, Wq, Wk, Wv, Wo, xb);
  // QKV: 128x192 tiles -> grid 32x16 = 512 blocks = 2 blocks/CU (+XCD swz)
  gemm_qkv_kernel<<<dim3(32, 16), 256, 0, stream>>>(xb, Wqkv, bq, bk, bv,
                                                    QKV);
  // attn: CHUNK=128 -> 512 blocks = 2 blocks/CU
  attn_kernel<<<512, 128, 0, stream>>>(QKV, ctx);
  // O: 64x128 tiles -> grid 64x8 = 512 blocks = 2 blocks/CU (+XCD swz)
  gemm_o_kernel<<<dim3(64, 8), 128, 0, stream>>>(ctx, Wob, bo, out);
}

// Round 20
// 68.179 us; speedup vs baseline: 1.1967x; 1.0108x over previous
//
#include <hip/hip_runtime.h>
#include <hip/hip_bf16.h>

typedef __bf16 bf16_t;
typedef __bf16 bf16x4 __attribute__((ext_vector_type(4)));
typedef __bf16 bf16x8 __attribute__((ext_vector_type(8)));
typedef float f32x4 __attribute__((ext_vector_type(4)));

#define S_LEN 2048
#define DMODEL 1024
#define NHEADS 16
#define HDIM 64
#define BROWS 4096   // B * S
#define QKVN 3072    // fused QKV output width

__device__ __forceinline__ void async16(const void* g, void* l) {
  __builtin_amdgcn_global_load_lds(
      (const __attribute__((address_space(1))) void*)g,
      (__attribute__((address_space(3))) void*)l, 16, 0, 0);
}

// ------------- fused f32 -> bf16 conversion (x, Wq, Wk, Wv, Wo) -------------
__global__ __launch_bounds__(256) void cvt_all_kernel(
    const float* __restrict__ x, const float* __restrict__ Wq,
    const float* __restrict__ Wk, const float* __restrict__ Wv,
    const float* __restrict__ Wo, bf16_t* __restrict__ dst) {
  const int i = blockIdx.x * 256 + threadIdx.x;  // float4 index
  constexpr int XN4 = (BROWS * DMODEL) / 4;      // 1048576
  constexpr int WN4 = (DMODEL * DMODEL) / 4;     // 262144
  const float* src;
  size_t off;
  if (i < XN4) {
    src = x;
    off = (size_t)i;
  } else {
    const int wi = i - XN4;
    const int w = wi >> 18;
    off = (size_t)(wi & (WN4 - 1));
    src = (w == 0) ? Wq : (w == 1) ? Wk : (w == 2) ? Wv : Wo;
  }
  const float4 v = *(const float4*)(src + off * 4);
  bf16x4 o;
  o[0] = (bf16_t)v.x;
  o[1] = (bf16_t)v.y;
  o[2] = (bf16_t)v.z;
  o[3] = (bf16_t)v.w;
  *(bf16x4*)(dst + (size_t)i * 4) = o;
}

#define BARR __builtin_amdgcn_s_barrier()
#define LGKM0 asm volatile("s_waitcnt lgkmcnt(0)" ::: "memory")
#define VMC10 asm volatile("s_waitcnt vmcnt(10)" ::: "memory")
#define VMC12 asm volatile("s_waitcnt vmcnt(12)" ::: "memory")
#define VMC0 asm volatile("s_waitcnt vmcnt(0)" ::: "memory")

// ========== 128x192 GEMM (QKV): 2 blocks/CU, independent barrier domains ====
// (r15/r16 best-measured config: reads -> LGKM0 -> BARR#1 -> stage(t+2) ->
//  MFMA -> VMC(<=10) -> BARR#2; 10 stage-instr/tile; swizzle slot^(r&7).)
__global__ __launch_bounds__(256, 2) void gemm_qkv_kernel(
    const bf16_t* __restrict__ A, const bf16_t* __restrict__ W,
    const float* __restrict__ bq, const float* __restrict__ bk,
    const float* __restrict__ bv, bf16_t* __restrict__ C) {
  constexpr int Kd = 1024;
  __shared__ char lds[81920];  // A: 2buf*16KB, B: 2buf*24KB = 80KB
  char* ldsA = lds;            // + buf*16384
  char* ldsB = lds + 32768;    // + buf*24576

  const int m0 = blockIdx.x * 128;
  const int n0 = blockIdx.y * 192;

  const int tid = threadIdx.x;
  const int lane = tid & 63;
  const int wid = tid >> 6;   // 0..3
  const int wr = wid >> 1;    // 0..1 (64 rows each)
  const int wc = wid & 1;     // 0..1 (96 cols each)
  const int fr = lane & 15;
  const int l16 = lane >> 4;

  f32x4 acc[4][6] = {};
  bf16x8 aS[4][2], bB[6][2];

  auto stageA = [&](int buf, int kt) {
#pragma unroll
    for (int l = 0; l < 4; ++l) {
      const int idx = l * 256 + tid;
      const int r = idx >> 3;  // 0..127
      const int slot = idx & 7;
      async16((const char*)(A + (size_t)(m0 + r) * Kd + kt * 64 +
                            ((slot ^ (r & 7)) << 3)),
              ldsA + buf * 16384 + r * 128 + slot * 16);
    }
  };
  auto stageB = [&](int buf, int kt) {
#pragma unroll
    for (int l = 0; l < 6; ++l) {
      const int idx = l * 256 + tid;
      const int r = idx >> 3;  // 0..191
      const int slot = idx & 7;
      async16((const char*)(W + (size_t)(n0 + r) * Kd + kt * 64 +
                            ((slot ^ (r & 7)) << 3)),
              ldsB + buf * 24576 + r * 128 + slot * 16);
    }
  };

  auto rdA = [&](int buf, int row, int ks) -> bf16x8 {
    return *(const bf16x8*)(ldsA + buf * 16384 + row * 128 +
                            ((((ks << 2) + l16) ^ (row & 7)) << 4));
  };
  auto rdB = [&](int buf, int row, int ks) -> bf16x8 {
    return *(const bf16x8*)(ldsB + buf * 24576 + row * 128 +
                            ((((ks << 2) + l16) ^ (row & 7)) << 4));
  };

  stageA(0, 0);
  stageB(0, 0);
  stageA(1, 1);
  stageB(1, 1);
  VMC10;  // 20 outstanding -> retire oldest 10 = all of tile0 (own)
  BARR;   // barrier-release certifies tile0 across all waves

#pragma unroll 1
  for (int t = 0; t < 16; ++t) {
    const int buf = t & 1;
#pragma unroll
    for (int m_ = 0; m_ < 4; ++m_)
#pragma unroll
      for (int ks_ = 0; ks_ < 2; ++ks_)
        aS[m_][ks_] = rdA(buf, wr * 64 + m_ * 16 + fr, ks_);
#pragma unroll
    for (int n_ = 0; n_ < 6; ++n_)
#pragma unroll
      for (int ks_ = 0; ks_ < 2; ++ks_)
        bB[n_][ks_] = rdB(buf, wc * 96 + n_ * 16 + fr, ks_);
    LGKM0;  // own reads retired...
    BARR;   // ...all waves' reads retired -> buf safe to overwrite
    if (t + 2 < 16) {
      stageA(buf, t + 2);
      stageB(buf, t + 2);
    }
    __builtin_amdgcn_s_setprio(1);
#pragma unroll
    for (int m_ = 0; m_ < 4; ++m_)
#pragma unroll
      for (int n_ = 0; n_ < 6; ++n_)
#pragma unroll
        for (int ks_ = 0; ks_ < 2; ++ks_)
          acc[m_][n_] = __builtin_amdgcn_mfma_f32_16x16x32_bf16(
              aS[m_][ks_], bB[n_][ks_], acc[m_][n_], 0, 0, 0);
    __builtin_amdgcn_s_setprio(0);
    if (t < 15) {
      if (t + 2 < 16) {
        VMC10;  // outstanding t+1's 10 + t+2's 10 -> retire t+1's
      } else {
        VMC0;   // t=14: only t15's 10 outstanding
      }
      BARR;
    }
  }

  // epilogue: C/D layout col = lane&15, row = (lane>>4)*4 + reg  [m89]
  const int cr = l16 * 4;
#pragma unroll
  for (int nf = 0; nf < 6; ++nf) {
    const int col = n0 + wc * 96 + nf * 16 + fr;  // 0..3071
    const int mat = col >> 10;
    const float* bp = (mat == 0) ? bq : (mat == 1) ? bk : bv;
    const float bval = bp[col & 1023];
#pragma unroll
    for (int mf = 0; mf < 4; ++mf) {
      const int row = m0 + wr * 64 + mf * 16 + cr;
#pragma unroll
      for (int r = 0; r < 4; ++r)
        C[(size_t)(row + r) * QKVN + col] = (bf16_t)(acc[mf][nf][r] + bval);
    }
  }
}

// ====== 64x128 GEMM (O-proj): r16 verified, 2 waves, 2 blocks/CU ============
__global__ __launch_bounds__(128) void gemm_o_kernel(
    const bf16_t* __restrict__ A, const bf16_t* __restrict__ W,
    const float* __restrict__ bias, float* __restrict__ out) {
  constexpr int Kd = 1024, Nd = 1024;
  __shared__ char lds[49152];  // A: 2buf*8KB = 16KB, B: 2buf*16KB = 32KB
  char* ldsA = lds;            // + buf*8192
  char* ldsB = lds + 16384;    // + buf*16384

  const int m0 = blockIdx.x * 64;
  const int n0 = blockIdx.y * 128;

  const int tid = threadIdx.x;  // 0..127
  const int lane = tid & 63;
  const int wid = tid >> 6;  // 0..1 (64-col halves)
  const int fr = lane & 15;
  const int l16 = lane >> 4;

  f32x4 acc[4][4] = {};
  bf16x8 aS[4][2], bB[4][2];

  auto stageA = [&](int buf, int kt) {
#pragma unroll
    for (int l = 0; l < 4; ++l) {
      const int idx = l * 128 + tid;
      const int r = idx >> 3;  // 0..63
      const int slot = idx & 7;
      async16((const char*)(A + (size_t)(m0 + r) * Kd + kt * 64 +
                            ((slot ^ (r & 7)) << 3)),
              ldsA + buf * 8192 + r * 128 + slot * 16);
    }
  };
  auto stageB = [&](int buf, int kt) {
#pragma unroll
    for (int l = 0; l < 8; ++l) {
      const int idx = l * 128 + tid;
      const int r = idx >> 3;  // 0..127
      const int slot = idx & 7;
      async16((const char*)(W + (size_t)(n0 + r) * Kd + kt * 64 +
                            ((slot ^ (r & 7)) << 3)),
              ldsB + buf * 16384 + r * 128 + slot * 16);
    }
  };

  auto rdA = [&](int buf, int row, int ks) -> bf16x8 {
    return *(const bf16x8*)(ldsA + buf * 8192 + row * 128 +
                            ((((ks << 2) + l16) ^ (row & 7)) << 4));
  };
  auto rdB = [&](int buf, int row, int ks) -> bf16x8 {
    return *(const bf16x8*)(ldsB + buf * 16384 + row * 128 +
                            ((((ks << 2) + l16) ^ (row & 7)) << 4));
  };

  stageA(0, 0);
  stageB(0, 0);
  stageA(1, 1);
  stageB(1, 1);
  VMC12;  // 24 outstanding -> retire oldest 12 = all of tile0 (own)
  BARR;

#pragma unroll 1
  for (int t = 0; t < 16; ++t) {
    const int buf = t & 1;
#pragma unroll
    for (int m_ = 0; m_ < 4; ++m_)
#pragma unroll
      for (int ks_ = 0; ks_ < 2; ++ks_)
        aS[m_][ks_] = rdA(buf, m_ * 16 + fr, ks_);
#pragma unroll
    for (int n_ = 0; n_ < 4; ++n_)
#pragma unroll
      for (int ks_ = 0; ks_ < 2; ++ks_)
        bB[n_][ks_] = rdB(buf, wid * 64 + n_ * 16 + fr, ks_);
    LGKM0;
    BARR;
    if (t + 2 < 16) {
      stageA(buf, t + 2);
      stageB(buf, t + 2);
    }
    __builtin_amdgcn_s_setprio(1);
#pragma unroll
    for (int m_ = 0; m_ < 4; ++m_)
#pragma unroll
      for (int n_ = 0; n_ < 4; ++n_)
#pragma unroll
        for (int ks_ = 0; ks_ < 2; ++ks_)
          acc[m_][n_] = __builtin_amdgcn_mfma_f32_16x16x32_bf16(
              aS[m_][ks_], bB[n_][ks_], acc[m_][n_], 0, 0, 0);
    __builtin_amdgcn_s_setprio(0);
    if (t < 15) {
      if (t + 2 < 16) {
        VMC12;
      } else {
        VMC0;
      }
      BARR;
    }
  }

  const int cr = l16 * 4;
#pragma unroll
  for (int nf = 0; nf < 4; ++nf) {
    const int col = n0 + wid * 64 + nf * 16 + fr;  // 0..1023
    const float bval = bias[col];
#pragma unroll
    for (int mf = 0; mf < 4; ++mf) {
      const int row = m0 + mf * 16 + cr;
#pragma unroll
      for (int r = 0; r < 4; ++r)
        out[(size_t)(row + r) * Nd + col] = acc[mf][nf][r] + bval;
    }
  }
}

// ---------------- local attention (thread-per-query, fused QKV in) ---------
#define CHUNK 256
#define TROWS 260

__global__ __launch_bounds__(256) void attn_kernel(
    const bf16_t* __restrict__ QKV, bf16_t* __restrict__ ctx) {
  __shared__ bf16_t ldsK[TROWS * HDIM];
  __shared__ bf16_t ldsV[TROWS * HDIM];

  const int tid = threadIdx.x;
  const int blk = blockIdx.x;
  const int chunk = blk & 7;
  const int bh = blk >> 3;
  const int h = bh & (NHEADS - 1);
  const int b = bh >> 4;
  const int s0 = chunk * CHUNK;

  const bf16_t* Kb = QKV + (size_t)b * S_LEN * QKVN + DMODEL + h * HDIM;
  const bf16_t* Vb = QKV + (size_t)b * S_LEN * QKVN + 2 * DMODEL + h * HDIM;

#pragma unroll
  for (int j = 0; j < 9; ++j) {
    const int i = j * 256 + tid;
    if (i < TROWS * 8) {
      const int tr = i >> 3;
      const int slot = i & 7;
      const int c = slot ^ (tr & 7);
      int gs = s0 - 2 + tr;
      gs = (gs < 0) ? 0 : (gs >= S_LEN ? S_LEN - 1 : gs);
      async16((const char*)(Kb + (size_t)gs * QKVN) + c * 16,
              (char*)ldsK + i * 16);
      async16((const char*)(Vb + (size_t)gs * QKVN) + c * 16,
              (char*)ldsV + i * 16);
    }
  }

  const int s = s0 + tid;
  const bf16_t* Qrow = QKV + ((size_t)(b * S_LEN) + s) * QKVN + h * HDIM;
  bf16x8 q8[8];
#pragma unroll
  for (int c = 0; c < 8; ++c) q8[c] = *(const bf16x8*)(Qrow + c * 8);
  float qf[64];
#pragma unroll
  for (int c = 0; c < 8; ++c)
#pragma unroll
    for (int e = 0; e < 8; ++e) qf[c * 8 + e] = (float)q8[c][e];

  __syncthreads();

  float sc[5];
#pragma unroll
  for (int jj = 0; jj < 5; ++jj) {
    const int tr = tid + jj;
    float d = 0.f;
#pragma unroll
    for (int c = 0; c < 8; ++c) {
      const bf16x8 k8 = *(const bf16x8*)(ldsK + tr * HDIM + (c ^ (tr & 7)) * 8);
#pragma unroll
      for (int e = 0; e < 8; ++e) d += qf[c * 8 + e] * (float)k8[e];
    }
    const int j = s - 2 + jj;
    sc[jj] = (j < 0 || j >= S_LEN) ? -1e30f : d * 0.125f;
  }

  float m = sc[0];
#pragma unroll
  for (int jj = 1; jj < 5; ++jj) m = fmaxf(m, sc[jj]);
  float p[5], l = 0.f;
#pragma unroll
  for (int jj = 0; jj < 5; ++jj) {
    p[jj] = __expf(sc[jj] - m);
    l += p[jj];
  }
  const float inv = 1.0f / l;
#pragma unroll
  for (int jj = 0; jj < 5; ++jj) p[jj] *= inv;

  float o[64];
#pragma unroll
  for (int e = 0; e < 64; ++e) o[e] = 0.f;
#pragma unroll
  for (int jj = 0; jj < 5; ++jj) {
    const int tr = tid + jj;
    const float pj = p[jj];
#pragma unroll
    for (int c = 0; c < 8; ++c) {
      const bf16x8 v8 = *(const bf16x8*)(ldsV + tr * HDIM + (c ^ (tr & 7)) * 8);
#pragma unroll
      for (int e = 0; e < 8; ++e) o[c * 8 + e] += pj * (float)v8[e];
    }
  }

  bf16_t* Crow = (bf16_t*)ctx + ((size_t)(b * S_LEN) + s) * DMODEL + h * HDIM;
#pragma unroll
  for (int c = 0; c < 8; ++c) {
    bf16x8 ov;
#pragma unroll
    for (int e = 0; e < 8; ++e) ov[e] = (bf16_t)o[c * 8 + e];
    *(bf16x8*)(Crow + c * 8) = ov;
  }
}

extern "C" void kernel_launch(void* const* d_in, const int* in_sizes, int n_in,
                              void* d_out, int out_size, void* d_ws,
                              size_t ws_size, hipStream_t stream) {
  const float* x = (const float*)d_in[0];
  const float* Wq = (const float*)d_in[1];
  const float* bq = (const float*)d_in[2];
  const float* Wk = (const float*)d_in[3];
  const float* bk = (const float*)d_in[4];
  const float* Wv = (const float*)d_in[5];
  const float* bv = (const float*)d_in[6];
  const float* Wo = (const float*)d_in[7];
  const float* bo = (const float*)d_in[8];
  float* out = (float*)d_out;

  const size_t mat = (size_t)BROWS * DMODEL;
  const size_t wmat = (size_t)DMODEL * DMODEL;
  bf16_t* xb = (bf16_t*)d_ws;   // [xb | Wqkv | Wob] contiguous (cvt dst)
  bf16_t* Wqkv = xb + mat;      // fused [3072][1024]
  bf16_t* Wob = Wqkv + 3 * wmat;
  bf16_t* QKV = Wob + wmat;     // fused [4096][3072]
  bf16_t* ctx = QKV + 3 * mat;

  cvt_all_kernel<<<8192, 256, 0, stream>>>(x, Wq, Wk, Wv, Wo, xb);
  // QKV: 128x192 tiles -> grid 32x16 = 512 blocks = 2 blocks/CU
  gemm_qkv_kernel<<<dim3(32, 16), 256, 0, stream>>>(xb, Wqkv, bq, bk, bv,
                                                    QKV);
  attn_kernel<<<256, 256, 0, stream>>>(QKV, ctx);
  // O: 64x128 tiles -> grid 64x8 = 512 blocks = 2 blocks/CU
  gemm_o_kernel<<<dim3(64, 8), 128, 0, stream>>>(ctx, Wob, bo, out);
}